// Round 9
// baseline (403.316 us; speedup 1.0000x reference)
//
#include <hip/hip_runtime.h>
#include <hip/hip_bf16.h>
#include <math.h>

#define HID 128
#define NSB 128   // stats partial slots
#define NBLK_BIN 256
#define BINC_CAP 6144

typedef short short8 __attribute__((ext_vector_type(8)));
typedef float f32x4 __attribute__((ext_vector_type(4)));

// ---------------- prep: zero bucket counters + zero pstats + pad x + build MFMA-swizzled bf16 hi/lo weights ----------------
__global__ void prep_kernel(const float* __restrict__ x, float* __restrict__ xp,
                            int* __restrict__ bcnt, int nbuck16,
                            float* __restrict__ pstats, int npstats,
                            const float* __restrict__ Wn0, const float* __restrict__ Wr0,
                            const float* __restrict__ Wn1, const float* __restrict__ Wr1,
                            const float* __restrict__ Wn2, const float* __restrict__ Wr2,
                            unsigned short* __restrict__ B0h, unsigned short* __restrict__ B0l,
                            unsigned short* __restrict__ B1h, unsigned short* __restrict__ B1l,
                            unsigned short* __restrict__ B2h, unsigned short* __restrict__ B2l,
                            int N, int K0, int K0pad) {
    int i = blockIdx.x * blockDim.x + threadIdx.x;
    if (i < nbuck16) bcnt[i] = 0;
    if (i < npstats) pstats[i] = 0.f;   // atomic-accumulated by fused agg
    if (i < N * K0pad) {
        int row = i / K0pad;
        int c = i - row * K0pad;
        xp[i] = (c < K0) ? x[(size_t)row * K0 + c] : 0.f;
    }
    int n0 = 256 * K0pad, n1 = 256 * HID;
    if (i < n0 + 2 * n1) {
        const float *Wn, *Wr;
        unsigned short *bh, *bl;
        int K, idx;
        if (i < n0) { Wn = Wn0; Wr = Wr0; bh = B0h; bl = B0l; K = K0; idx = i; }
        else if (i < n0 + n1) { Wn = Wn1; Wr = Wr1; bh = B1h; bl = B1l; K = HID; idx = i - n0; }
        else { Wn = Wn2; Wr = Wr2; bh = B2h; bl = B2l; K = HID; idx = i - n0 - n1; }
        int j = idx & 7;
        int lane = (idx >> 3) & 63;
        int cb = (idx >> 9) & 15;
        int ks = idx >> 13;
        int k = ks * 32 + ((lane >> 4) & 3) * 8 + j;
        int ch = 16 * cb + (lane & 15);
        float v = 0.f;
        if (k < K) v = (ch < 128) ? Wn[k * 128 + ch] : Wr[k * 128 + (ch - 128)];
        __hip_bfloat16 h = __float2bfloat16(v);
        float hf = __bfloat162float(h);
        __hip_bfloat16 l = __float2bfloat16(v - hf);
        bh[idx] = *(unsigned short*)&h;
        bl[idx] = *(unsigned short*)&l;
    }
}

// ---------------- CSR build: two-level bucketed counting sort ----------------
__global__ void binA_kernel(const int* __restrict__ dst, int* __restrict__ bcnt,
                            int ne, int nbuck, int shift) {
    __shared__ int hist[512];
    int t = threadIdx.x;
    for (int i = t; i < 512; i += 256) hist[i] = 0;
    __syncthreads();
    size_t beg = (size_t)ne * blockIdx.x / NBLK_BIN;
    size_t end = (size_t)ne * (blockIdx.x + 1) / NBLK_BIN;
    for (size_t e = beg + t; e < end; e += 256)
        atomicAdd(&hist[dst[e] >> shift], 1);
    __syncthreads();
    for (int b = t; b < nbuck; b += 256) {
        int h = hist[b];
        if (h) atomicAdd(&bcnt[b * 16], h);
    }
}

__global__ __launch_bounds__(512) void bucket_scan_kernel(const int* __restrict__ bcnt,
                                                          int* __restrict__ bbase,
                                                          int* __restrict__ bcur, int nbuck) {
    __shared__ int tmp[512];
    int t = threadIdx.x;
    int v = (t < nbuck) ? bcnt[t * 16] : 0;
    tmp[t] = v;
    __syncthreads();
    for (int off = 1; off < 512; off <<= 1) {
        int u = 0;
        if (t >= off) u = tmp[t - off];
        __syncthreads();
        if (t >= off) tmp[t] += u;
        __syncthreads();
    }
    if (t < nbuck) {
        int exc = tmp[t] - v;
        bbase[t] = exc;
        bcur[t * 16] = exc;
        if (t == nbuck - 1) bbase[nbuck] = tmp[t];
    }
}

__global__ void binB_kernel(const int* __restrict__ src, const int* __restrict__ dst,
                            int* __restrict__ bcur, uint2* __restrict__ ebuf,
                            int ne, int nbuck, int shift) {
    __shared__ int hist[512];
    __shared__ int base[512];
    int t = threadIdx.x;
    for (int i = t; i < 512; i += 256) hist[i] = 0;
    __syncthreads();
    size_t beg = (size_t)ne * blockIdx.x / NBLK_BIN;
    size_t end = (size_t)ne * (blockIdx.x + 1) / NBLK_BIN;
    for (size_t e = beg + t; e < end; e += 256)
        atomicAdd(&hist[dst[e] >> shift], 1);
    __syncthreads();
    for (int b = t; b < nbuck; b += 256) {
        int h = hist[b];
        if (h) base[b] = atomicAdd(&bcur[b * 16], h);
        hist[b] = 0;
    }
    __syncthreads();
    for (size_t e = beg + t; e < end; e += 256) {
        int d = dst[e];
        int bk = d >> shift;
        int r = atomicAdd(&hist[bk], 1);
        ebuf[base[bk] + r] = make_uint2((unsigned)src[e], (unsigned)d);
    }
}

__global__ __launch_bounds__(512) void binC_kernel(const uint2* __restrict__ ebuf,
                                                   const int* __restrict__ bbase,
                                                   int* __restrict__ counts,
                                                   int* __restrict__ offsets,
                                                   int* __restrict__ esrc,
                                                   int N, int shift) {
    __shared__ int cnt[512], tmp[512], cur[512];
    __shared__ int sout[BINC_CAP];
    int b = blockIdx.x;
    int t = threadIdx.x;
    int node0 = b << shift;
    int npb = 1 << shift;
    if (node0 + npb > N) npb = N - node0;
    int ebase = bbase[b];
    int eend = bbase[b + 1];
    int total = eend - ebase;
    cnt[t] = 0;
    __syncthreads();
    for (int e = ebase + t; e < eend; e += 512)
        atomicAdd(&cnt[ebuf[e].y - node0], 1);
    __syncthreads();
    int v = cnt[t];
    tmp[t] = v;
    __syncthreads();
    for (int off = 1; off < 512; off <<= 1) {
        int u = 0;
        if (t >= off) u = tmp[t - off];
        __syncthreads();
        if (t >= off) tmp[t] += u;
        __syncthreads();
    }
    int exc = tmp[t] - v;
    cur[t] = exc;
    if (t < npb) {
        counts[node0 + t] = v;
        offsets[node0 + t] = ebase + exc;
    }
    __syncthreads();
    if (total <= BINC_CAP) {
        for (int e = ebase + t; e < eend; e += 512) {
            uint2 p = ebuf[e];
            int r = atomicAdd(&cur[(int)p.y - node0], 1);
            sout[r] = (int)p.x;
        }
        __syncthreads();
        for (int k = t; k < total; k += 512)
            esrc[ebase + k] = sout[k];
    } else {
        for (int e = ebase + t; e < eend; e += 512) {
            uint2 p = ebuf[e];
            int r = atomicAdd(&cur[(int)p.y - node0], 1);
            esrc[ebase + r] = (int)p.x;
        }
    }
}

// ---------------- MFMA dual GEMM (R8-proven): 32x256 tile, T14 load-issue-first,
// 2x-parallel BN finalize ----------------
template <int KPAD>
__global__ __launch_bounds__(256) void gemm_kernel(
    const float* __restrict__ A,
    const float* __restrict__ psum, const float* __restrict__ psumsq,
    const float* __restrict__ g, const float* __restrict__ be,
    const unsigned short* __restrict__ Bswh, const unsigned short* __restrict__ Bswl,
    unsigned short* __restrict__ U16, float* __restrict__ V, int N) {
    constexpr int LSTR = KPAD + 8;
    constexpr int KSTEPS = KPAD / 32;
    constexpr int ITERS = (32 * KPAD) / 1024;
    int tid = threadIdx.x;
    int lane = tid & 63;
    int w = tid >> 6;
    int q = lane >> 4;
    int m = lane & 15;
    int n0 = blockIdx.x * 32;
    int apply_bn = (psum != nullptr);

    __shared__ float s_sc[HID], s_sh[HID];
    __shared__ double s_pS[2][HID], s_pQ[2][HID];
    __shared__ unsigned short sA_h[32 * LSTR], sA_l[32 * LSTR];

    // (1) issue A-tile loads FIRST -- latency hides under BN finalize below
    float4 zreg[ITERS];
#pragma unroll
    for (int it = 0; it < ITERS; it++) {
        int idx = tid * 4 + it * 1024;
        int row = idx / KPAD;
        int col = idx - row * KPAD;
        int grow = n0 + row;
        if (grow >= N) grow = N - 1;
        zreg[it] = *(const float4*)(A + (size_t)grow * KPAD + col);
    }

    // (2) BN finalize, 2x parallel: thread t sums b in [half*64, half*64+64) for ch t&127
    if (apply_bn) {
        int ch = tid & 127;
        int half = tid >> 7;
        double S = 0.0, Q = 0.0;
        for (int b = half * (NSB / 2); b < (half + 1) * (NSB / 2); b++) {
            S += (double)psum[b * HID + ch];
            Q += (double)psumsq[b * HID + ch];
        }
        s_pS[half][ch] = S;
        s_pQ[half][ch] = Q;
        __syncthreads();
        if (tid < HID) {
            double St = s_pS[0][tid] + s_pS[1][tid];
            double Qt = s_pQ[0][tid] + s_pQ[1][tid];
            double mu = St / (double)N;
            double var = Qt / (double)N - mu * mu;
            if (var < 0.0) var = 0.0;
            float rs = (float)(1.0 / sqrt(var + 1e-5));
            float sc = g[tid] * rs;
            s_sc[tid] = sc;
            s_sh[tid] = be[tid] - (float)mu * sc;
        }
        __syncthreads();
    }

#pragma unroll
    for (int it = 0; it < ITERS; it++) {
        int idx = tid * 4 + it * 1024;
        int row = idx / KPAD;
        int col = idx - row * KPAD;
        float y[4] = {zreg[it].x, zreg[it].y, zreg[it].z, zreg[it].w};
        if (apply_bn) {
#pragma unroll
            for (int j = 0; j < 4; j++)
                y[j] = fmaxf(fmaf(y[j], s_sc[col + j], s_sh[col + j]), 0.f);
        }
        ushort4 h4, l4;
        unsigned short* ph = (unsigned short*)&h4;
        unsigned short* pl = (unsigned short*)&l4;
#pragma unroll
        for (int j = 0; j < 4; j++) {
            __hip_bfloat16 h = __float2bfloat16(y[j]);
            float hf = __bfloat162float(h);
            __hip_bfloat16 lo = __float2bfloat16(y[j] - hf);
            ph[j] = *(unsigned short*)&h;
            pl[j] = *(unsigned short*)&lo;
        }
        *(ushort4*)&sA_h[row * LSTR + col] = h4;
        *(ushort4*)&sA_l[row * LSTR + col] = l4;
    }
    __syncthreads();

    f32x4 acc[2][4];
#pragma unroll
    for (int r = 0; r < 2; r++)
#pragma unroll
        for (int c = 0; c < 4; c++) acc[r][c] = (f32x4){0.f, 0.f, 0.f, 0.f};

#pragma unroll
    for (int ks = 0; ks < KSTEPS; ks++) {
        int ko = ks * 32 + q * 8;
        short8 ah[2], al[2], bh[4], bl[4];
#pragma unroll
        for (int c = 0; c < 4; c++) {
            int cb = 4 * w + c;
            size_t off = ((size_t)(ks * 16 + cb) * 64 + lane) * 8;
            bh[c] = __builtin_bit_cast(short8, *(const uint4*)(Bswh + off));
            bl[c] = __builtin_bit_cast(short8, *(const uint4*)(Bswl + off));
        }
#pragma unroll
        for (int r = 0; r < 2; r++) {
            int ao = (16 * r + m) * LSTR + ko;
            ah[r] = __builtin_bit_cast(short8, *(uint4*)&sA_h[ao]);
            al[r] = __builtin_bit_cast(short8, *(uint4*)&sA_l[ao]);
        }
#pragma unroll
        for (int r = 0; r < 2; r++)
#pragma unroll
            for (int c = 0; c < 4; c++) {
                acc[r][c] = __builtin_amdgcn_mfma_f32_16x16x32_bf16(ah[r], bh[c], acc[r][c], 0, 0, 0);
                acc[r][c] = __builtin_amdgcn_mfma_f32_16x16x32_bf16(ah[r], bl[c], acc[r][c], 0, 0, 0);
                acc[r][c] = __builtin_amdgcn_mfma_f32_16x16x32_bf16(al[r], bh[c], acc[r][c], 0, 0, 0);
            }
    }
    int colbase = (w & 1) * 64;
    if (w < 2) {
#pragma unroll
        for (int r = 0; r < 2; r++)
#pragma unroll
            for (int c = 0; c < 4; c++) {
                int col = colbase + 16 * c + m;
#pragma unroll
                for (int i = 0; i < 4; i++) {
                    int row = n0 + 16 * r + 4 * q + i;
                    if (row < N) {
                        __hip_bfloat16 h = __float2bfloat16(acc[r][c][i]);
                        U16[(size_t)row * HID + col] = *(unsigned short*)&h;
                    }
                }
            }
    } else {
#pragma unroll
        for (int r = 0; r < 2; r++)
#pragma unroll
            for (int c = 0; c < 4; c++) {
                int col = colbase + 16 * c + m;
#pragma unroll
                for (int i = 0; i < 4; i++) {
                    int row = n0 + 16 * r + 4 * q + i;
                    if (row < N) V[(size_t)row * HID + col] = acc[r][c][i];
                }
            }
    }
}

// ---------------- aggregation (R6 layout) + fused stats; R9: 16-deep gather unroll.
// agg is gather-LATENCY-bound (37% BW, 29% VALU): mean deg~16 ran the 8-deep loop
// as 2 serial latency exposures; 16-deep puts all 16 row-gathers in flight at once. ----------------
__global__ __launch_bounds__(256) void agg_kernel(const unsigned short* __restrict__ U16,
                                                  const float* __restrict__ V,
                                                  const float* __restrict__ bias,
                                                  const int* __restrict__ counts,
                                                  const int* __restrict__ offsets,
                                                  const int* __restrict__ esrc,
                                                  float* __restrict__ Z,
                                                  float* __restrict__ psum,
                                                  float* __restrict__ psumsq, int N) {
    int grp = threadIdx.x >> 5;
    int l32 = threadIdx.x & 31;
    int n = blockIdx.x * 8 + grp;
    bool valid = (n < N);
    f32x4 z = (f32x4){0.f, 0.f, 0.f, 0.f};

    if (valid) {
        int deg = counts[n];
        int st = offsets[n];
        int co = 4 * l32;

        auto cvt = [](uint2 raw) -> f32x4 {
            f32x4 v;
            v[0] = __uint_as_float(raw.x << 16);
            v[1] = __uint_as_float(raw.x & 0xffff0000u);
            v[2] = __uint_as_float(raw.y << 16);
            v[3] = __uint_as_float(raw.y & 0xffff0000u);
            return v;
        };

        f32x4 a0 = {0,0,0,0}, a1 = {0,0,0,0}, a2 = {0,0,0,0}, a3 = {0,0,0,0};
        f32x4 a4 = {0,0,0,0}, a5 = {0,0,0,0}, a6 = {0,0,0,0}, a7 = {0,0,0,0};
        int i = 0;
        for (; i + 15 < deg; i += 16) {
            int ss[16];
#pragma unroll
            for (int k = 0; k < 16; k++) ss[k] = esrc[st + i + k];
            uint2 rr[16];
#pragma unroll
            for (int k = 0; k < 16; k++)
                rr[k] = *(const uint2*)(U16 + (size_t)ss[k] * HID + co);
            a0 += cvt(rr[0]) + cvt(rr[8]);
            a1 += cvt(rr[1]) + cvt(rr[9]);
            a2 += cvt(rr[2]) + cvt(rr[10]);
            a3 += cvt(rr[3]) + cvt(rr[11]);
            a4 += cvt(rr[4]) + cvt(rr[12]);
            a5 += cvt(rr[5]) + cvt(rr[13]);
            a6 += cvt(rr[6]) + cvt(rr[14]);
            a7 += cvt(rr[7]) + cvt(rr[15]);
        }
        for (; i + 7 < deg; i += 8) {
            int s0 = esrc[st + i + 0], s1 = esrc[st + i + 1];
            int s2 = esrc[st + i + 2], s3 = esrc[st + i + 3];
            int s4 = esrc[st + i + 4], s5 = esrc[st + i + 5];
            int s6 = esrc[st + i + 6], s7 = esrc[st + i + 7];
            uint2 r0 = *(const uint2*)(U16 + (size_t)s0 * HID + co);
            uint2 r1 = *(const uint2*)(U16 + (size_t)s1 * HID + co);
            uint2 r2 = *(const uint2*)(U16 + (size_t)s2 * HID + co);
            uint2 r3 = *(const uint2*)(U16 + (size_t)s3 * HID + co);
            uint2 r4 = *(const uint2*)(U16 + (size_t)s4 * HID + co);
            uint2 r5 = *(const uint2*)(U16 + (size_t)s5 * HID + co);
            uint2 r6 = *(const uint2*)(U16 + (size_t)s6 * HID + co);
            uint2 r7 = *(const uint2*)(U16 + (size_t)s7 * HID + co);
            a0 += cvt(r0); a1 += cvt(r1); a2 += cvt(r2); a3 += cvt(r3);
            a4 += cvt(r4); a5 += cvt(r5); a6 += cvt(r6); a7 += cvt(r7);
        }
        for (; i + 3 < deg; i += 4) {
            int s0 = esrc[st + i + 0], s1 = esrc[st + i + 1];
            int s2 = esrc[st + i + 2], s3 = esrc[st + i + 3];
            uint2 r0 = *(const uint2*)(U16 + (size_t)s0 * HID + co);
            uint2 r1 = *(const uint2*)(U16 + (size_t)s1 * HID + co);
            uint2 r2 = *(const uint2*)(U16 + (size_t)s2 * HID + co);
            uint2 r3 = *(const uint2*)(U16 + (size_t)s3 * HID + co);
            a0 += cvt(r0); a1 += cvt(r1); a2 += cvt(r2); a3 += cvt(r3);
        }
        for (; i < deg; i++) {
            uint2 r0 = *(const uint2*)(U16 + (size_t)esrc[st + i] * HID + co);
            a0 += cvt(r0);
        }
        f32x4 acc = ((a0 + a1) + (a2 + a3)) + ((a4 + a5) + (a6 + a7));
        float d = (float)(deg > 1 ? deg : 1);
        f32x4 vv = ((const f32x4*)V)[(size_t)n * 32 + l32];
        f32x4 bb = ((const f32x4*)bias)[l32];
        z = acc / d + vv + bb;
        ((f32x4*)Z)[(size_t)n * 32 + l32] = z;
    }

    // fused stats: reduce the block's 8 nodes, one atomic pass per block
    __shared__ f32x4 bs[256], bq[256];
    int t = threadIdx.x;
    bs[t] = z;
    bq[t] = z * z;
    __syncthreads();
#pragma unroll
    for (int off = 4; off > 0; off >>= 1) {
        if (grp < off) {
            bs[t] += bs[t + off * 32];
            bq[t] += bq[t + off * 32];
        }
        __syncthreads();
    }
    if (grp == 0) {
        int slot = blockIdx.x & (NSB - 1);
        float* ps = psum + (size_t)slot * HID + 4 * l32;
        float* pq = psumsq + (size_t)slot * HID + 4 * l32;
        f32x4 s = bs[t];
        f32x4 qq = bq[t];
#pragma unroll
        for (int j = 0; j < 4; j++) {
            atomicAdd(&ps[j], s[j]);
            atomicAdd(&pq[j], qq[j]);
        }
    }
}

// ---------------- fused BN-finalize + BN+ReLU + segmented mean pool + MLP head ----------------
__global__ __launch_bounds__(128) void pool_head_kernel(const float* __restrict__ Z,
                                                        const float* __restrict__ psum,
                                                        const float* __restrict__ psumsq,
                                                        const float* __restrict__ g,
                                                        const float* __restrict__ be,
                                                        const int* __restrict__ batch,
                                                        const float* __restrict__ Wh1,
                                                        const float* __restrict__ bh1,
                                                        const float* __restrict__ Wh2,
                                                        const float* __restrict__ bh2,
                                                        float* __restrict__ out, int N) {
    int gph = blockIdx.x;
    __shared__ int bounds[2];
    __shared__ float p[128];
    int t = threadIdx.x;
    if (t < 2) {
        int target = gph + t;
        int lo = 0, hi = N;
        while (lo < hi) {
            int mid = (lo + hi) >> 1;
            if (batch[mid] < target) lo = mid + 1;
            else hi = mid;
        }
        bounds[t] = lo;
    }
    double S = 0.0, Q = 0.0;
    for (int b = 0; b < NSB; b++) {
        S += (double)psum[b * HID + t];
        Q += (double)psumsq[b * HID + t];
    }
    double mu = S / (double)N;
    double var = Q / (double)N - mu * mu;
    if (var < 0.0) var = 0.0;
    float rs = (float)(1.0 / sqrt(var + 1e-5));
    float sc = g[t] * rs;
    float sh = be[t] - (float)mu * sc;
    __syncthreads();
    int start = bounds[0], end = bounds[1];
    float s = 0.f;
    for (int n = start; n < end; n++)
        s += fmaxf(fmaf(Z[(size_t)n * HID + t], sc, sh), 0.f);
    p[t] = s / fmaxf((float)(end - start), 1.f);
    __syncthreads();
    if (t < 64) {
        float acc = bh1[t];
        for (int k = 0; k < 128; k++) acc = fmaf(p[k], Wh1[k * 64 + t], acc);
        acc = fmaxf(acc, 0.f);
        float prod = acc * Wh2[t];
        for (int off = 32; off > 0; off >>= 1) prod += __shfl_down(prod, off);
        if (t == 0) out[gph] = prod + bh2[0];
    }
}

extern "C" void kernel_launch(void* const* d_in, const int* in_sizes, int n_in,
                              void* d_out, int out_size, void* d_ws, size_t ws_size,
                              hipStream_t stream) {
    const float* x = (const float*)d_in[0];
    const int* ei = (const int*)d_in[1];
    const int* batch = (const int*)d_in[2];
    const float* Wn[3] = {(const float*)d_in[3], (const float*)d_in[8], (const float*)d_in[13]};
    const float* bb[3] = {(const float*)d_in[4], (const float*)d_in[9], (const float*)d_in[14]};
    const float* Wr[3] = {(const float*)d_in[5], (const float*)d_in[10], (const float*)d_in[15]};
    const float* gg[3] = {(const float*)d_in[6], (const float*)d_in[11], (const float*)d_in[16]};
    const float* be[3] = {(const float*)d_in[7], (const float*)d_in[12], (const float*)d_in[17]};
    const float* Wh1 = (const float*)d_in[18];
    const float* bh1 = (const float*)d_in[19];
    const float* Wh2 = (const float*)d_in[20];
    const float* bh2 = (const float*)d_in[21];
    float* out = (float*)d_out;

    const int N = in_sizes[2];       // 50000
    const int NE = in_sizes[1] / 2;  // 800000
    const int NG = out_size;         // 1000
    const int K0 = in_sizes[0] / N;  // 78
    const int K0pad = (K0 <= 96) ? 96 : 128;  // template-dispatched KPAD (K0 <= 128)

    const int* src = ei;
    const int* dst = ei + NE;

    // bucket geometry: <=512 buckets, <=512 nodes/bucket (N<=262144)
    int shift = 7;
    int nbuck = (N + 127) >> 7;
    while (nbuck > 512) { shift++; nbuck = (N + (1 << shift) - 1) >> shift; }

    char* w = (char*)d_ws;
    auto alloc = [&](size_t bytes) -> void* {
        void* p = (void*)w;
        w += (bytes + 255) & ~(size_t)255;
        return p;
    };
    unsigned short* bufU16 = (unsigned short*)alloc((size_t)N * HID * 2);
    float* bufV = (float*)alloc((size_t)N * HID * 4);
    float* bufZ = (float*)alloc((size_t)N * HID * 4);
    float* xp = (float*)alloc((size_t)N * K0pad * 4);
    unsigned short* BTh[3];
    unsigned short* BTl[3];
    BTh[0] = (unsigned short*)alloc((size_t)256 * K0pad * 2);
    BTl[0] = (unsigned short*)alloc((size_t)256 * K0pad * 2);
    BTh[1] = (unsigned short*)alloc((size_t)256 * HID * 2);
    BTl[1] = (unsigned short*)alloc((size_t)256 * HID * 2);
    BTh[2] = (unsigned short*)alloc((size_t)256 * HID * 2);
    BTl[2] = (unsigned short*)alloc((size_t)256 * HID * 2);
    int* counts = (int*)alloc((size_t)N * 4);
    int* offsets = (int*)alloc((size_t)(N + 1) * 4);
    int* esrc = (int*)alloc((size_t)NE * 4);
    int* bcnt = (int*)alloc((size_t)512 * 16 * 4);   // padded: 1 counter / 64B line
    int* bcur = (int*)alloc((size_t)512 * 16 * 4);
    int* bbase = (int*)alloc((size_t)(512 + 1) * 4);
    float* pstats = (float*)alloc((size_t)3 * 2 * NSB * HID * 4);
    // ebuf (NE*8 = 6.4MB) only live during CSR build, before bufZ's first write -> alias.
    uint2* ebuf = (uint2*)bufZ;
    (void)ws_size;
    (void)n_in;

    const int npstats = 3 * 2 * NSB * HID;

    // ---- prep (zero bucket counters + zero pstats + pad x + swizzled weights) ----
    size_t prep_total = (size_t)N * K0pad;
    prep_kernel<<<(prep_total + 255) / 256, 256, 0, stream>>>(
        x, xp, bcnt, nbuck * 16, pstats, npstats,
        Wn[0], Wr[0], Wn[1], Wr[1], Wn[2], Wr[2],
        BTh[0], BTl[0], BTh[1], BTl[1], BTh[2], BTl[2], N, K0, K0pad);

    // ---- CSR via bucketed counting sort ----
    binA_kernel<<<NBLK_BIN, 256, 0, stream>>>(dst, bcnt, NE, nbuck, shift);
    bucket_scan_kernel<<<1, 512, 0, stream>>>(bcnt, bbase, bcur, nbuck);
    binB_kernel<<<NBLK_BIN, 256, 0, stream>>>(src, dst, bcur, ebuf, NE, nbuck, shift);
    binC_kernel<<<nbuck, 512, 0, stream>>>(ebuf, bbase, counts, offsets, esrc, N, shift);

    // ---- 3 SAGE layers: gemm(inline prev-BN finalize+apply) -> agg(+fused stats) ----
    int gblocks = (N + 31) / 32;
    int ablocks = (N + 7) / 8;
    for (int l = 0; l < 3; l++) {
        const float* Ain = (l == 0) ? xp : bufZ;
        int Kpad = (l == 0) ? K0pad : HID;
        const float* ppsum = (l == 0) ? (const float*)nullptr : pstats + (size_t)(l - 1) * 2 * NSB * HID;
        const float* ppsq = (l == 0) ? (const float*)nullptr : pstats + (size_t)(l - 1) * 2 * NSB * HID + NSB * HID;
        const float* pg = (l == 0) ? (const float*)nullptr : gg[l - 1];
        const float* pb = (l == 0) ? (const float*)nullptr : be[l - 1];
        if (Kpad == 96)
            gemm_kernel<96><<<gblocks, 256, 0, stream>>>(Ain, ppsum, ppsq, pg, pb,
                                                         BTh[l], BTl[l], bufU16, bufV, N);
        else
            gemm_kernel<128><<<gblocks, 256, 0, stream>>>(Ain, ppsum, ppsq, pg, pb,
                                                          BTh[l], BTl[l], bufU16, bufV, N);
        agg_kernel<<<ablocks, 256, 0, stream>>>(bufU16, bufV, bb[l], counts, offsets, esrc, bufZ,
                                                pstats + (size_t)l * 2 * NSB * HID,
                                                pstats + (size_t)l * 2 * NSB * HID + NSB * HID, N);
    }

    // ---- fused BN-finalize + BN+ReLU + pool + head ----
    pool_head_kernel<<<NG, 128, 0, stream>>>(bufZ,
                                             pstats + (size_t)2 * 2 * NSB * HID,
                                             pstats + (size_t)2 * 2 * NSB * HID + NSB * HID,
                                             gg[2], be[2], batch, Wh1, bh1, Wh2, bh2, out, N);
}

// Round 10
// 374.766 us; speedup vs baseline: 1.0762x; 1.0762x over previous
//
#include <hip/hip_runtime.h>
#include <hip/hip_bf16.h>
#include <math.h>

#define HID 128
#define NSB 128   // stats partial slots
#define NBLK_BIN 256
#define BINC_CAP 6144

typedef short short8 __attribute__((ext_vector_type(8)));
typedef float f32x4 __attribute__((ext_vector_type(4)));

// ---------------- prep: zero bucket counters + zero pstats + pad x + build MFMA-swizzled bf16 hi/lo weights ----------------
__global__ void prep_kernel(const float* __restrict__ x, float* __restrict__ xp,
                            int* __restrict__ bcnt, int nbuck16,
                            float* __restrict__ pstats, int npstats,
                            const float* __restrict__ Wn0, const float* __restrict__ Wr0,
                            const float* __restrict__ Wn1, const float* __restrict__ Wr1,
                            const float* __restrict__ Wn2, const float* __restrict__ Wr2,
                            unsigned short* __restrict__ B0h, unsigned short* __restrict__ B0l,
                            unsigned short* __restrict__ B1h, unsigned short* __restrict__ B1l,
                            unsigned short* __restrict__ B2h, unsigned short* __restrict__ B2l,
                            int N, int K0, int K0pad) {
    int i = blockIdx.x * blockDim.x + threadIdx.x;
    if (i < nbuck16) bcnt[i] = 0;
    if (i < npstats) pstats[i] = 0.f;   // atomic-accumulated by fused agg
    if (i < N * K0pad) {
        int row = i / K0pad;
        int c = i - row * K0pad;
        xp[i] = (c < K0) ? x[(size_t)row * K0 + c] : 0.f;
    }
    int n0 = 256 * K0pad, n1 = 256 * HID;
    if (i < n0 + 2 * n1) {
        const float *Wn, *Wr;
        unsigned short *bh, *bl;
        int K, idx;
        if (i < n0) { Wn = Wn0; Wr = Wr0; bh = B0h; bl = B0l; K = K0; idx = i; }
        else if (i < n0 + n1) { Wn = Wn1; Wr = Wr1; bh = B1h; bl = B1l; K = HID; idx = i - n0; }
        else { Wn = Wn2; Wr = Wr2; bh = B2h; bl = B2l; K = HID; idx = i - n0 - n1; }
        int j = idx & 7;
        int lane = (idx >> 3) & 63;
        int cb = (idx >> 9) & 15;
        int ks = idx >> 13;
        int k = ks * 32 + ((lane >> 4) & 3) * 8 + j;
        int ch = 16 * cb + (lane & 15);
        float v = 0.f;
        if (k < K) v = (ch < 128) ? Wn[k * 128 + ch] : Wr[k * 128 + (ch - 128)];
        __hip_bfloat16 h = __float2bfloat16(v);
        float hf = __bfloat162float(h);
        __hip_bfloat16 l = __float2bfloat16(v - hf);
        bh[idx] = *(unsigned short*)&h;
        bl[idx] = *(unsigned short*)&l;
    }
}

// ---------------- CSR build: two-level bucketed counting sort ----------------
__global__ void binA_kernel(const int* __restrict__ dst, int* __restrict__ bcnt,
                            int ne, int nbuck, int shift) {
    __shared__ int hist[512];
    int t = threadIdx.x;
    for (int i = t; i < 512; i += 256) hist[i] = 0;
    __syncthreads();
    size_t beg = (size_t)ne * blockIdx.x / NBLK_BIN;
    size_t end = (size_t)ne * (blockIdx.x + 1) / NBLK_BIN;
    for (size_t e = beg + t; e < end; e += 256)
        atomicAdd(&hist[dst[e] >> shift], 1);
    __syncthreads();
    for (int b = t; b < nbuck; b += 256) {
        int h = hist[b];
        if (h) atomicAdd(&bcnt[b * 16], h);
    }
}

__global__ __launch_bounds__(512) void bucket_scan_kernel(const int* __restrict__ bcnt,
                                                          int* __restrict__ bbase,
                                                          int* __restrict__ bcur, int nbuck) {
    __shared__ int tmp[512];
    int t = threadIdx.x;
    int v = (t < nbuck) ? bcnt[t * 16] : 0;
    tmp[t] = v;
    __syncthreads();
    for (int off = 1; off < 512; off <<= 1) {
        int u = 0;
        if (t >= off) u = tmp[t - off];
        __syncthreads();
        if (t >= off) tmp[t] += u;
        __syncthreads();
    }
    if (t < nbuck) {
        int exc = tmp[t] - v;
        bbase[t] = exc;
        bcur[t * 16] = exc;
        if (t == nbuck - 1) bbase[nbuck] = tmp[t];
    }
}

__global__ void binB_kernel(const int* __restrict__ src, const int* __restrict__ dst,
                            int* __restrict__ bcur, uint2* __restrict__ ebuf,
                            int ne, int nbuck, int shift) {
    __shared__ int hist[512];
    __shared__ int base[512];
    int t = threadIdx.x;
    for (int i = t; i < 512; i += 256) hist[i] = 0;
    __syncthreads();
    size_t beg = (size_t)ne * blockIdx.x / NBLK_BIN;
    size_t end = (size_t)ne * (blockIdx.x + 1) / NBLK_BIN;
    for (size_t e = beg + t; e < end; e += 256)
        atomicAdd(&hist[dst[e] >> shift], 1);
    __syncthreads();
    for (int b = t; b < nbuck; b += 256) {
        int h = hist[b];
        if (h) base[b] = atomicAdd(&bcur[b * 16], h);
        hist[b] = 0;
    }
    __syncthreads();
    for (size_t e = beg + t; e < end; e += 256) {
        int d = dst[e];
        int bk = d >> shift;
        int r = atomicAdd(&hist[bk], 1);
        ebuf[base[bk] + r] = make_uint2((unsigned)src[e], (unsigned)d);
    }
}

__global__ __launch_bounds__(512) void binC_kernel(const uint2* __restrict__ ebuf,
                                                   const int* __restrict__ bbase,
                                                   int* __restrict__ counts,
                                                   int* __restrict__ offsets,
                                                   int* __restrict__ esrc,
                                                   int N, int shift) {
    __shared__ int cnt[512], tmp[512], cur[512];
    __shared__ int sout[BINC_CAP];
    int b = blockIdx.x;
    int t = threadIdx.x;
    int node0 = b << shift;
    int npb = 1 << shift;
    if (node0 + npb > N) npb = N - node0;
    int ebase = bbase[b];
    int eend = bbase[b + 1];
    int total = eend - ebase;
    cnt[t] = 0;
    __syncthreads();
    for (int e = ebase + t; e < eend; e += 512)
        atomicAdd(&cnt[ebuf[e].y - node0], 1);
    __syncthreads();
    int v = cnt[t];
    tmp[t] = v;
    __syncthreads();
    for (int off = 1; off < 512; off <<= 1) {
        int u = 0;
        if (t >= off) u = tmp[t - off];
        __syncthreads();
        if (t >= off) tmp[t] += u;
        __syncthreads();
    }
    int exc = tmp[t] - v;
    cur[t] = exc;
    if (t < npb) {
        counts[node0 + t] = v;
        offsets[node0 + t] = ebase + exc;
    }
    __syncthreads();
    if (total <= BINC_CAP) {
        for (int e = ebase + t; e < eend; e += 512) {
            uint2 p = ebuf[e];
            int r = atomicAdd(&cur[(int)p.y - node0], 1);
            sout[r] = (int)p.x;
        }
        __syncthreads();
        for (int k = t; k < total; k += 512)
            esrc[ebase + k] = sout[k];
    } else {
        for (int e = ebase + t; e < eend; e += 512) {
            uint2 p = ebuf[e];
            int r = atomicAdd(&cur[(int)p.y - node0], 1);
            esrc[ebase + r] = (int)p.x;
        }
    }
}

// ---------------- MFMA dual GEMM (R8-proven): 32x256 tile, T14 load-issue-first,
// 2x-parallel BN finalize ----------------
template <int KPAD>
__global__ __launch_bounds__(256) void gemm_kernel(
    const float* __restrict__ A,
    const float* __restrict__ psum, const float* __restrict__ psumsq,
    const float* __restrict__ g, const float* __restrict__ be,
    const unsigned short* __restrict__ Bswh, const unsigned short* __restrict__ Bswl,
    unsigned short* __restrict__ U16, float* __restrict__ V, int N) {
    constexpr int LSTR = KPAD + 8;
    constexpr int KSTEPS = KPAD / 32;
    constexpr int ITERS = (32 * KPAD) / 1024;
    int tid = threadIdx.x;
    int lane = tid & 63;
    int w = tid >> 6;
    int q = lane >> 4;
    int m = lane & 15;
    int n0 = blockIdx.x * 32;
    int apply_bn = (psum != nullptr);

    __shared__ float s_sc[HID], s_sh[HID];
    __shared__ double s_pS[2][HID], s_pQ[2][HID];
    __shared__ unsigned short sA_h[32 * LSTR], sA_l[32 * LSTR];

    // (1) issue A-tile loads FIRST -- latency hides under BN finalize below
    float4 zreg[ITERS];
#pragma unroll
    for (int it = 0; it < ITERS; it++) {
        int idx = tid * 4 + it * 1024;
        int row = idx / KPAD;
        int col = idx - row * KPAD;
        int grow = n0 + row;
        if (grow >= N) grow = N - 1;
        zreg[it] = *(const float4*)(A + (size_t)grow * KPAD + col);
    }

    // (2) BN finalize, 2x parallel: thread t sums b in [half*64, half*64+64) for ch t&127
    if (apply_bn) {
        int ch = tid & 127;
        int half = tid >> 7;
        double S = 0.0, Q = 0.0;
        for (int b = half * (NSB / 2); b < (half + 1) * (NSB / 2); b++) {
            S += (double)psum[b * HID + ch];
            Q += (double)psumsq[b * HID + ch];
        }
        s_pS[half][ch] = S;
        s_pQ[half][ch] = Q;
        __syncthreads();
        if (tid < HID) {
            double St = s_pS[0][tid] + s_pS[1][tid];
            double Qt = s_pQ[0][tid] + s_pQ[1][tid];
            double mu = St / (double)N;
            double var = Qt / (double)N - mu * mu;
            if (var < 0.0) var = 0.0;
            float rs = (float)(1.0 / sqrt(var + 1e-5));
            float sc = g[tid] * rs;
            s_sc[tid] = sc;
            s_sh[tid] = be[tid] - (float)mu * sc;
        }
        __syncthreads();
    }

#pragma unroll
    for (int it = 0; it < ITERS; it++) {
        int idx = tid * 4 + it * 1024;
        int row = idx / KPAD;
        int col = idx - row * KPAD;
        float y[4] = {zreg[it].x, zreg[it].y, zreg[it].z, zreg[it].w};
        if (apply_bn) {
#pragma unroll
            for (int j = 0; j < 4; j++)
                y[j] = fmaxf(fmaf(y[j], s_sc[col + j], s_sh[col + j]), 0.f);
        }
        ushort4 h4, l4;
        unsigned short* ph = (unsigned short*)&h4;
        unsigned short* pl = (unsigned short*)&l4;
#pragma unroll
        for (int j = 0; j < 4; j++) {
            __hip_bfloat16 h = __float2bfloat16(y[j]);
            float hf = __bfloat162float(h);
            __hip_bfloat16 lo = __float2bfloat16(y[j] - hf);
            ph[j] = *(unsigned short*)&h;
            pl[j] = *(unsigned short*)&lo;
        }
        *(ushort4*)&sA_h[row * LSTR + col] = h4;
        *(ushort4*)&sA_l[row * LSTR + col] = l4;
    }
    __syncthreads();

    f32x4 acc[2][4];
#pragma unroll
    for (int r = 0; r < 2; r++)
#pragma unroll
        for (int c = 0; c < 4; c++) acc[r][c] = (f32x4){0.f, 0.f, 0.f, 0.f};

#pragma unroll
    for (int ks = 0; ks < KSTEPS; ks++) {
        int ko = ks * 32 + q * 8;
        short8 ah[2], al[2], bh[4], bl[4];
#pragma unroll
        for (int c = 0; c < 4; c++) {
            int cb = 4 * w + c;
            size_t off = ((size_t)(ks * 16 + cb) * 64 + lane) * 8;
            bh[c] = __builtin_bit_cast(short8, *(const uint4*)(Bswh + off));
            bl[c] = __builtin_bit_cast(short8, *(const uint4*)(Bswl + off));
        }
#pragma unroll
        for (int r = 0; r < 2; r++) {
            int ao = (16 * r + m) * LSTR + ko;
            ah[r] = __builtin_bit_cast(short8, *(uint4*)&sA_h[ao]);
            al[r] = __builtin_bit_cast(short8, *(uint4*)&sA_l[ao]);
        }
#pragma unroll
        for (int r = 0; r < 2; r++)
#pragma unroll
            for (int c = 0; c < 4; c++) {
                acc[r][c] = __builtin_amdgcn_mfma_f32_16x16x32_bf16(ah[r], bh[c], acc[r][c], 0, 0, 0);
                acc[r][c] = __builtin_amdgcn_mfma_f32_16x16x32_bf16(ah[r], bl[c], acc[r][c], 0, 0, 0);
                acc[r][c] = __builtin_amdgcn_mfma_f32_16x16x32_bf16(al[r], bh[c], acc[r][c], 0, 0, 0);
            }
    }
    int colbase = (w & 1) * 64;
    if (w < 2) {
#pragma unroll
        for (int r = 0; r < 2; r++)
#pragma unroll
            for (int c = 0; c < 4; c++) {
                int col = colbase + 16 * c + m;
#pragma unroll
                for (int i = 0; i < 4; i++) {
                    int row = n0 + 16 * r + 4 * q + i;
                    if (row < N) {
                        __hip_bfloat16 h = __float2bfloat16(acc[r][c][i]);
                        U16[(size_t)row * HID + col] = *(unsigned short*)&h;
                    }
                }
            }
    } else {
#pragma unroll
        for (int r = 0; r < 2; r++)
#pragma unroll
            for (int c = 0; c < 4; c++) {
                int col = colbase + 16 * c + m;
#pragma unroll
                for (int i = 0; i < 4; i++) {
                    int row = n0 + 16 * r + 4 * q + i;
                    if (row < N) V[(size_t)row * HID + col] = acc[r][c][i];
                }
            }
    }
}

// ---------------- aggregation (R8-proven: 8 nodes/block, 32-lane uint2, 8-deep,
// full-wave coalesced Z stores) + fused BN stats. R9 lesson: 16-deep unroll raised
// VGPR 40->56, occupancy 50->33%, dur +4us -> keep 8-deep. ----------------
__global__ __launch_bounds__(256) void agg_kernel(const unsigned short* __restrict__ U16,
                                                  const float* __restrict__ V,
                                                  const float* __restrict__ bias,
                                                  const int* __restrict__ counts,
                                                  const int* __restrict__ offsets,
                                                  const int* __restrict__ esrc,
                                                  float* __restrict__ Z,
                                                  float* __restrict__ psum,
                                                  float* __restrict__ psumsq, int N) {
    int grp = threadIdx.x >> 5;
    int l32 = threadIdx.x & 31;
    int n = blockIdx.x * 8 + grp;
    bool valid = (n < N);
    f32x4 z = (f32x4){0.f, 0.f, 0.f, 0.f};

    if (valid) {
        int deg = counts[n];
        int st = offsets[n];
        int co = 4 * l32;

        auto cvt = [](uint2 raw) -> f32x4 {
            f32x4 v;
            v[0] = __uint_as_float(raw.x << 16);
            v[1] = __uint_as_float(raw.x & 0xffff0000u);
            v[2] = __uint_as_float(raw.y << 16);
            v[3] = __uint_as_float(raw.y & 0xffff0000u);
            return v;
        };

        f32x4 a0 = {0,0,0,0}, a1 = {0,0,0,0}, a2 = {0,0,0,0}, a3 = {0,0,0,0};
        f32x4 a4 = {0,0,0,0}, a5 = {0,0,0,0}, a6 = {0,0,0,0}, a7 = {0,0,0,0};
        int i = 0;
        for (; i + 7 < deg; i += 8) {
            int s0 = esrc[st + i + 0], s1 = esrc[st + i + 1];
            int s2 = esrc[st + i + 2], s3 = esrc[st + i + 3];
            int s4 = esrc[st + i + 4], s5 = esrc[st + i + 5];
            int s6 = esrc[st + i + 6], s7 = esrc[st + i + 7];
            uint2 r0 = *(const uint2*)(U16 + (size_t)s0 * HID + co);
            uint2 r1 = *(const uint2*)(U16 + (size_t)s1 * HID + co);
            uint2 r2 = *(const uint2*)(U16 + (size_t)s2 * HID + co);
            uint2 r3 = *(const uint2*)(U16 + (size_t)s3 * HID + co);
            uint2 r4 = *(const uint2*)(U16 + (size_t)s4 * HID + co);
            uint2 r5 = *(const uint2*)(U16 + (size_t)s5 * HID + co);
            uint2 r6 = *(const uint2*)(U16 + (size_t)s6 * HID + co);
            uint2 r7 = *(const uint2*)(U16 + (size_t)s7 * HID + co);
            a0 += cvt(r0); a1 += cvt(r1); a2 += cvt(r2); a3 += cvt(r3);
            a4 += cvt(r4); a5 += cvt(r5); a6 += cvt(r6); a7 += cvt(r7);
        }
        for (; i + 3 < deg; i += 4) {
            int s0 = esrc[st + i + 0], s1 = esrc[st + i + 1];
            int s2 = esrc[st + i + 2], s3 = esrc[st + i + 3];
            uint2 r0 = *(const uint2*)(U16 + (size_t)s0 * HID + co);
            uint2 r1 = *(const uint2*)(U16 + (size_t)s1 * HID + co);
            uint2 r2 = *(const uint2*)(U16 + (size_t)s2 * HID + co);
            uint2 r3 = *(const uint2*)(U16 + (size_t)s3 * HID + co);
            a0 += cvt(r0); a1 += cvt(r1); a2 += cvt(r2); a3 += cvt(r3);
        }
        for (; i < deg; i++) {
            uint2 r0 = *(const uint2*)(U16 + (size_t)esrc[st + i] * HID + co);
            a0 += cvt(r0);
        }
        f32x4 acc = ((a0 + a1) + (a2 + a3)) + ((a4 + a5) + (a6 + a7));
        float d = (float)(deg > 1 ? deg : 1);
        f32x4 vv = ((const f32x4*)V)[(size_t)n * 32 + l32];
        f32x4 bb = ((const f32x4*)bias)[l32];
        z = acc / d + vv + bb;
        ((f32x4*)Z)[(size_t)n * 32 + l32] = z;
    }

    // fused stats: reduce the block's 8 nodes, one atomic pass per block
    __shared__ f32x4 bs[256], bq[256];
    int t = threadIdx.x;
    bs[t] = z;
    bq[t] = z * z;
    __syncthreads();
#pragma unroll
    for (int off = 4; off > 0; off >>= 1) {
        if (grp < off) {
            bs[t] += bs[t + off * 32];
            bq[t] += bq[t + off * 32];
        }
        __syncthreads();
    }
    if (grp == 0) {
        int slot = blockIdx.x & (NSB - 1);
        float* ps = psum + (size_t)slot * HID + 4 * l32;
        float* pq = psumsq + (size_t)slot * HID + 4 * l32;
        f32x4 s = bs[t];
        f32x4 qq = bq[t];
#pragma unroll
        for (int j = 0; j < 4; j++) {
            atomicAdd(&ps[j], s[j]);
            atomicAdd(&pq[j], qq[j]);
        }
    }
}

// ---------------- fused BN-finalize + BN+ReLU + pool + MLP head. R10: 256 threads;
// finalize 2x-parallel (64 serial iters, like gemm's R8 fix) and the per-graph node
// loop 2x-split across thread-halves (evens/odds, LDS combine). ----------------
__global__ __launch_bounds__(256) void pool_head_kernel(const float* __restrict__ Z,
                                                        const float* __restrict__ psum,
                                                        const float* __restrict__ psumsq,
                                                        const float* __restrict__ g,
                                                        const float* __restrict__ be,
                                                        const int* __restrict__ batch,
                                                        const float* __restrict__ Wh1,
                                                        const float* __restrict__ bh1,
                                                        const float* __restrict__ Wh2,
                                                        const float* __restrict__ bh2,
                                                        float* __restrict__ out, int N) {
    int gph = blockIdx.x;
    __shared__ int bounds[2];
    __shared__ float pp[2][HID];
    __shared__ double s_pS[2][HID], s_pQ[2][HID];
    __shared__ float s_sc[HID], s_sh[HID];
    int t = threadIdx.x;
    int ch = t & 127;
    int half = t >> 7;
    if (t < 2) {
        int target = gph + t;
        int lo = 0, hi = N;
        while (lo < hi) {
            int mid = (lo + hi) >> 1;
            if (batch[mid] < target) lo = mid + 1;
            else hi = mid;
        }
        bounds[t] = lo;
    }
    // 2x-parallel BN finalize
    {
        double S = 0.0, Q = 0.0;
        for (int b = half * (NSB / 2); b < (half + 1) * (NSB / 2); b++) {
            S += (double)psum[b * HID + ch];
            Q += (double)psumsq[b * HID + ch];
        }
        s_pS[half][ch] = S;
        s_pQ[half][ch] = Q;
    }
    __syncthreads();
    if (t < HID) {
        double St = s_pS[0][t] + s_pS[1][t];
        double Qt = s_pQ[0][t] + s_pQ[1][t];
        double mu = St / (double)N;
        double var = Qt / (double)N - mu * mu;
        if (var < 0.0) var = 0.0;
        float rs = (float)(1.0 / sqrt(var + 1e-5));
        float sc = g[t] * rs;
        s_sc[t] = sc;
        s_sh[t] = be[t] - (float)mu * sc;
    }
    __syncthreads();
    int start = bounds[0], end = bounds[1];
    // 2x-split pool loop: half h handles nodes start+h, start+h+2, ...
    {
        float sc = s_sc[ch];
        float sh = s_sh[ch];
        float s = 0.f;
        for (int n = start + half; n < end; n += 2)
            s += fmaxf(fmaf(Z[(size_t)n * HID + ch], sc, sh), 0.f);
        pp[half][ch] = s;
    }
    __syncthreads();
    if (t < HID)
        pp[0][t] = (pp[0][t] + pp[1][t]) / fmaxf((float)(end - start), 1.f);
    __syncthreads();
    if (t < 64) {
        float acc = bh1[t];
        for (int k = 0; k < 128; k++) acc = fmaf(pp[0][k], Wh1[k * 64 + t], acc);
        acc = fmaxf(acc, 0.f);
        float prod = acc * Wh2[t];
        for (int off = 32; off > 0; off >>= 1) prod += __shfl_down(prod, off);
        if (t == 0) out[gph] = prod + bh2[0];
    }
}

extern "C" void kernel_launch(void* const* d_in, const int* in_sizes, int n_in,
                              void* d_out, int out_size, void* d_ws, size_t ws_size,
                              hipStream_t stream) {
    const float* x = (const float*)d_in[0];
    const int* ei = (const int*)d_in[1];
    const int* batch = (const int*)d_in[2];
    const float* Wn[3] = {(const float*)d_in[3], (const float*)d_in[8], (const float*)d_in[13]};
    const float* bb[3] = {(const float*)d_in[4], (const float*)d_in[9], (const float*)d_in[14]};
    const float* Wr[3] = {(const float*)d_in[5], (const float*)d_in[10], (const float*)d_in[15]};
    const float* gg[3] = {(const float*)d_in[6], (const float*)d_in[11], (const float*)d_in[16]};
    const float* be[3] = {(const float*)d_in[7], (const float*)d_in[12], (const float*)d_in[17]};
    const float* Wh1 = (const float*)d_in[18];
    const float* bh1 = (const float*)d_in[19];
    const float* Wh2 = (const float*)d_in[20];
    const float* bh2 = (const float*)d_in[21];
    float* out = (float*)d_out;

    const int N = in_sizes[2];       // 50000
    const int NE = in_sizes[1] / 2;  // 800000
    const int NG = out_size;         // 1000
    const int K0 = in_sizes[0] / N;  // 78
    const int K0pad = (K0 <= 96) ? 96 : 128;  // template-dispatched KPAD (K0 <= 128)

    const int* src = ei;
    const int* dst = ei + NE;

    // bucket geometry: <=512 buckets, <=512 nodes/bucket (N<=262144)
    int shift = 7;
    int nbuck = (N + 127) >> 7;
    while (nbuck > 512) { shift++; nbuck = (N + (1 << shift) - 1) >> shift; }

    char* w = (char*)d_ws;
    auto alloc = [&](size_t bytes) -> void* {
        void* p = (void*)w;
        w += (bytes + 255) & ~(size_t)255;
        return p;
    };
    unsigned short* bufU16 = (unsigned short*)alloc((size_t)N * HID * 2);
    float* bufV = (float*)alloc((size_t)N * HID * 4);
    float* bufZ = (float*)alloc((size_t)N * HID * 4);
    float* xp = (float*)alloc((size_t)N * K0pad * 4);
    unsigned short* BTh[3];
    unsigned short* BTl[3];
    BTh[0] = (unsigned short*)alloc((size_t)256 * K0pad * 2);
    BTl[0] = (unsigned short*)alloc((size_t)256 * K0pad * 2);
    BTh[1] = (unsigned short*)alloc((size_t)256 * HID * 2);
    BTl[1] = (unsigned short*)alloc((size_t)256 * HID * 2);
    BTh[2] = (unsigned short*)alloc((size_t)256 * HID * 2);
    BTl[2] = (unsigned short*)alloc((size_t)256 * HID * 2);
    int* counts = (int*)alloc((size_t)N * 4);
    int* offsets = (int*)alloc((size_t)(N + 1) * 4);
    int* esrc = (int*)alloc((size_t)NE * 4);
    int* bcnt = (int*)alloc((size_t)512 * 16 * 4);   // padded: 1 counter / 64B line
    int* bcur = (int*)alloc((size_t)512 * 16 * 4);
    int* bbase = (int*)alloc((size_t)(512 + 1) * 4);
    float* pstats = (float*)alloc((size_t)3 * 2 * NSB * HID * 4);
    // ebuf (NE*8 = 6.4MB) only live during CSR build, before bufZ's first write -> alias.
    uint2* ebuf = (uint2*)bufZ;
    (void)ws_size;
    (void)n_in;

    const int npstats = 3 * 2 * NSB * HID;

    // ---- prep (zero bucket counters + zero pstats + pad x + swizzled weights) ----
    size_t prep_total = (size_t)N * K0pad;
    prep_kernel<<<(prep_total + 255) / 256, 256, 0, stream>>>(
        x, xp, bcnt, nbuck * 16, pstats, npstats,
        Wn[0], Wr[0], Wn[1], Wr[1], Wn[2], Wr[2],
        BTh[0], BTl[0], BTh[1], BTl[1], BTh[2], BTl[2], N, K0, K0pad);

    // ---- CSR via bucketed counting sort ----
    binA_kernel<<<NBLK_BIN, 256, 0, stream>>>(dst, bcnt, NE, nbuck, shift);
    bucket_scan_kernel<<<1, 512, 0, stream>>>(bcnt, bbase, bcur, nbuck);
    binB_kernel<<<NBLK_BIN, 256, 0, stream>>>(src, dst, bcur, ebuf, NE, nbuck, shift);
    binC_kernel<<<nbuck, 512, 0, stream>>>(ebuf, bbase, counts, offsets, esrc, N, shift);

    // ---- 3 SAGE layers: gemm(inline prev-BN finalize+apply) -> agg(+fused stats) ----
    int gblocks = (N + 31) / 32;
    int ablocks = (N + 7) / 8;
    for (int l = 0; l < 3; l++) {
        const float* Ain = (l == 0) ? xp : bufZ;
        int Kpad = (l == 0) ? K0pad : HID;
        const float* ppsum = (l == 0) ? (const float*)nullptr : pstats + (size_t)(l - 1) * 2 * NSB * HID;
        const float* ppsq = (l == 0) ? (const float*)nullptr : pstats + (size_t)(l - 1) * 2 * NSB * HID + NSB * HID;
        const float* pg = (l == 0) ? (const float*)nullptr : gg[l - 1];
        const float* pb = (l == 0) ? (const float*)nullptr : be[l - 1];
        if (Kpad == 96)
            gemm_kernel<96><<<gblocks, 256, 0, stream>>>(Ain, ppsum, ppsq, pg, pb,
                                                         BTh[l], BTl[l], bufU16, bufV, N);
        else
            gemm_kernel<128><<<gblocks, 256, 0, stream>>>(Ain, ppsum, ppsq, pg, pb,
                                                          BTh[l], BTl[l], bufU16, bufV, N);
        agg_kernel<<<ablocks, 256, 0, stream>>>(bufU16, bufV, bb[l], counts, offsets, esrc, bufZ,
                                                pstats + (size_t)l * 2 * NSB * HID,
                                                pstats + (size_t)l * 2 * NSB * HID + NSB * HID, N);
    }

    // ---- fused BN-finalize + BN+ReLU + pool + head ----
    pool_head_kernel<<<NG, 256, 0, stream>>>(bufZ,
                                             pstats + (size_t)2 * 2 * NSB * HID,
                                             pstats + (size_t)2 * 2 * NSB * HID + NSB * HID,
                                             gg[2], be[2], batch, Wh1, bh1, Wh2, bh2, out, N);
}

// Round 11
// 374.624 us; speedup vs baseline: 1.0766x; 1.0004x over previous
//
#include <hip/hip_runtime.h>
#include <hip/hip_bf16.h>
#include <math.h>

#define HID 128
#define NSB 128   // stats partial slots
#define NBLK_BIN 256
#define BINC_CAP 6144

typedef short short8 __attribute__((ext_vector_type(8)));
typedef float f32x4 __attribute__((ext_vector_type(4)));

// ---------------- prep: zero bucket counters + zero pstats + pad x + build MFMA-swizzled bf16 hi/lo weights ----------------
__global__ void prep_kernel(const float* __restrict__ x, float* __restrict__ xp,
                            int* __restrict__ bcnt, int nbuck16,
                            float* __restrict__ pstats, int npstats,
                            const float* __restrict__ Wn0, const float* __restrict__ Wr0,
                            const float* __restrict__ Wn1, const float* __restrict__ Wr1,
                            const float* __restrict__ Wn2, const float* __restrict__ Wr2,
                            unsigned short* __restrict__ B0h, unsigned short* __restrict__ B0l,
                            unsigned short* __restrict__ B1h, unsigned short* __restrict__ B1l,
                            unsigned short* __restrict__ B2h, unsigned short* __restrict__ B2l,
                            int N, int K0, int K0pad) {
    int i = blockIdx.x * blockDim.x + threadIdx.x;
    if (i < nbuck16) bcnt[i] = 0;
    if (i < npstats) pstats[i] = 0.f;   // atomic-accumulated by fused agg
    if (i < N * K0pad) {
        int row = i / K0pad;
        int c = i - row * K0pad;
        xp[i] = (c < K0) ? x[(size_t)row * K0 + c] : 0.f;
    }
    int n0 = 256 * K0pad, n1 = 256 * HID;
    if (i < n0 + 2 * n1) {
        const float *Wn, *Wr;
        unsigned short *bh, *bl;
        int K, idx;
        if (i < n0) { Wn = Wn0; Wr = Wr0; bh = B0h; bl = B0l; K = K0; idx = i; }
        else if (i < n0 + n1) { Wn = Wn1; Wr = Wr1; bh = B1h; bl = B1l; K = HID; idx = i - n0; }
        else { Wn = Wn2; Wr = Wr2; bh = B2h; bl = B2l; K = HID; idx = i - n0 - n1; }
        int j = idx & 7;
        int lane = (idx >> 3) & 63;
        int cb = (idx >> 9) & 15;
        int ks = idx >> 13;
        int k = ks * 32 + ((lane >> 4) & 3) * 8 + j;
        int ch = 16 * cb + (lane & 15);
        float v = 0.f;
        if (k < K) v = (ch < 128) ? Wn[k * 128 + ch] : Wr[k * 128 + (ch - 128)];
        __hip_bfloat16 h = __float2bfloat16(v);
        float hf = __bfloat162float(h);
        __hip_bfloat16 l = __float2bfloat16(v - hf);
        bh[idx] = *(unsigned short*)&h;
        bl[idx] = *(unsigned short*)&l;
    }
}

// ---------------- CSR build: two-level bucketed counting sort ----------------
__global__ void binA_kernel(const int* __restrict__ dst, int* __restrict__ bcnt,
                            int ne, int nbuck, int shift) {
    __shared__ int hist[512];
    int t = threadIdx.x;
    for (int i = t; i < 512; i += 256) hist[i] = 0;
    __syncthreads();
    size_t beg = (size_t)ne * blockIdx.x / NBLK_BIN;
    size_t end = (size_t)ne * (blockIdx.x + 1) / NBLK_BIN;
    for (size_t e = beg + t; e < end; e += 256)
        atomicAdd(&hist[dst[e] >> shift], 1);
    __syncthreads();
    for (int b = t; b < nbuck; b += 256) {
        int h = hist[b];
        if (h) atomicAdd(&bcnt[b * 16], h);
    }
}

__global__ __launch_bounds__(512) void bucket_scan_kernel(const int* __restrict__ bcnt,
                                                          int* __restrict__ bbase,
                                                          int* __restrict__ bcur, int nbuck) {
    __shared__ int tmp[512];
    int t = threadIdx.x;
    int v = (t < nbuck) ? bcnt[t * 16] : 0;
    tmp[t] = v;
    __syncthreads();
    for (int off = 1; off < 512; off <<= 1) {
        int u = 0;
        if (t >= off) u = tmp[t - off];
        __syncthreads();
        if (t >= off) tmp[t] += u;
        __syncthreads();
    }
    if (t < nbuck) {
        int exc = tmp[t] - v;
        bbase[t] = exc;
        bcur[t * 16] = exc;
        if (t == nbuck - 1) bbase[nbuck] = tmp[t];
    }
}

__global__ void binB_kernel(const int* __restrict__ src, const int* __restrict__ dst,
                            int* __restrict__ bcur, uint2* __restrict__ ebuf,
                            int ne, int nbuck, int shift) {
    __shared__ int hist[512];
    __shared__ int base[512];
    int t = threadIdx.x;
    for (int i = t; i < 512; i += 256) hist[i] = 0;
    __syncthreads();
    size_t beg = (size_t)ne * blockIdx.x / NBLK_BIN;
    size_t end = (size_t)ne * (blockIdx.x + 1) / NBLK_BIN;
    for (size_t e = beg + t; e < end; e += 256)
        atomicAdd(&hist[dst[e] >> shift], 1);
    __syncthreads();
    for (int b = t; b < nbuck; b += 256) {
        int h = hist[b];
        if (h) base[b] = atomicAdd(&bcur[b * 16], h);
        hist[b] = 0;
    }
    __syncthreads();
    for (size_t e = beg + t; e < end; e += 256) {
        int d = dst[e];
        int bk = d >> shift;
        int r = atomicAdd(&hist[bk], 1);
        ebuf[base[bk] + r] = make_uint2((unsigned)src[e], (unsigned)d);
    }
}

__global__ __launch_bounds__(512) void binC_kernel(const uint2* __restrict__ ebuf,
                                                   const int* __restrict__ bbase,
                                                   int* __restrict__ counts,
                                                   int* __restrict__ offsets,
                                                   int* __restrict__ esrc,
                                                   int N, int shift) {
    __shared__ int cnt[512], tmp[512], cur[512];
    __shared__ int sout[BINC_CAP];
    int b = blockIdx.x;
    int t = threadIdx.x;
    int node0 = b << shift;
    int npb = 1 << shift;
    if (node0 + npb > N) npb = N - node0;
    int ebase = bbase[b];
    int eend = bbase[b + 1];
    int total = eend - ebase;
    cnt[t] = 0;
    __syncthreads();
    for (int e = ebase + t; e < eend; e += 512)
        atomicAdd(&cnt[ebuf[e].y - node0], 1);
    __syncthreads();
    int v = cnt[t];
    tmp[t] = v;
    __syncthreads();
    for (int off = 1; off < 512; off <<= 1) {
        int u = 0;
        if (t >= off) u = tmp[t - off];
        __syncthreads();
        if (t >= off) tmp[t] += u;
        __syncthreads();
    }
    int exc = tmp[t] - v;
    cur[t] = exc;
    if (t < npb) {
        counts[node0 + t] = v;
        offsets[node0 + t] = ebase + exc;
    }
    __syncthreads();
    if (total <= BINC_CAP) {
        for (int e = ebase + t; e < eend; e += 512) {
            uint2 p = ebuf[e];
            int r = atomicAdd(&cur[(int)p.y - node0], 1);
            sout[r] = (int)p.x;
        }
        __syncthreads();
        for (int k = t; k < total; k += 512)
            esrc[ebase + k] = sout[k];
    } else {
        for (int e = ebase + t; e < eend; e += 512) {
            uint2 p = ebuf[e];
            int r = atomicAdd(&cur[(int)p.y - node0], 1);
            esrc[ebase + r] = (int)p.x;
        }
    }
}

// ---------------- BN finalize: ONE block computes sc/sh per layer. Removes the
// per-block 128KB psum/psumsq L2 stream from gemm (x1563 = 200MB/layer) and
// pool_head (x1000 = 128MB), and gemm's 4KB s_pS/s_pQ LDS. ----------------
__global__ __launch_bounds__(256) void bnfin_kernel(const float* __restrict__ psum,
                                                    const float* __restrict__ psumsq,
                                                    const float* __restrict__ g,
                                                    const float* __restrict__ be,
                                                    float* __restrict__ scsh, int N) {
    __shared__ double s_pS[2][HID], s_pQ[2][HID];
    int t = threadIdx.x;
    int ch = t & 127;
    int half = t >> 7;
    double S = 0.0, Q = 0.0;
    for (int b = half * (NSB / 2); b < (half + 1) * (NSB / 2); b++) {
        S += (double)psum[b * HID + ch];
        Q += (double)psumsq[b * HID + ch];
    }
    s_pS[half][ch] = S;
    s_pQ[half][ch] = Q;
    __syncthreads();
    if (t < HID) {
        double St = s_pS[0][t] + s_pS[1][t];
        double Qt = s_pQ[0][t] + s_pQ[1][t];
        double mu = St / (double)N;
        double var = Qt / (double)N - mu * mu;
        if (var < 0.0) var = 0.0;
        float rs = (float)(1.0 / sqrt(var + 1e-5));
        float sc = g[t] * rs;
        scsh[t] = sc;
        scsh[HID + t] = be[t] - (float)mu * sc;
    }
}

// ---------------- MFMA dual GEMM: 32x256 tile, T14 load-issue-first, precomputed
// sc/sh (1KB load replaces the 128KB per-block finalize stream) ----------------
template <int KPAD>
__global__ __launch_bounds__(256) void gemm_kernel(
    const float* __restrict__ A,
    const float* __restrict__ scsh,
    const unsigned short* __restrict__ Bswh, const unsigned short* __restrict__ Bswl,
    unsigned short* __restrict__ U16, float* __restrict__ V, int N) {
    constexpr int LSTR = KPAD + 8;
    constexpr int KSTEPS = KPAD / 32;
    constexpr int ITERS = (32 * KPAD) / 1024;
    int tid = threadIdx.x;
    int lane = tid & 63;
    int w = tid >> 6;
    int q = lane >> 4;
    int m = lane & 15;
    int n0 = blockIdx.x * 32;
    int apply_bn = (scsh != nullptr);

    __shared__ float s_sc[HID], s_sh[HID];
    __shared__ unsigned short sA_h[32 * LSTR], sA_l[32 * LSTR];

    // (1) issue A-tile loads FIRST (T14) -- latency hides under head below
    float4 zreg[ITERS];
#pragma unroll
    for (int it = 0; it < ITERS; it++) {
        int idx = tid * 4 + it * 1024;
        int row = idx / KPAD;
        int col = idx - row * KPAD;
        int grow = n0 + row;
        if (grow >= N) grow = N - 1;
        zreg[it] = *(const float4*)(A + (size_t)grow * KPAD + col);
    }

    // (2) load precomputed sc/sh (1KB)
    if (apply_bn) {
        if (tid < HID) {
            s_sc[tid] = scsh[tid];
            s_sh[tid] = scsh[HID + tid];
        }
        __syncthreads();
    }

#pragma unroll
    for (int it = 0; it < ITERS; it++) {
        int idx = tid * 4 + it * 1024;
        int row = idx / KPAD;
        int col = idx - row * KPAD;
        float y[4] = {zreg[it].x, zreg[it].y, zreg[it].z, zreg[it].w};
        if (apply_bn) {
#pragma unroll
            for (int j = 0; j < 4; j++)
                y[j] = fmaxf(fmaf(y[j], s_sc[col + j], s_sh[col + j]), 0.f);
        }
        ushort4 h4, l4;
        unsigned short* ph = (unsigned short*)&h4;
        unsigned short* pl = (unsigned short*)&l4;
#pragma unroll
        for (int j = 0; j < 4; j++) {
            __hip_bfloat16 h = __float2bfloat16(y[j]);
            float hf = __bfloat162float(h);
            __hip_bfloat16 lo = __float2bfloat16(y[j] - hf);
            ph[j] = *(unsigned short*)&h;
            pl[j] = *(unsigned short*)&lo;
        }
        *(ushort4*)&sA_h[row * LSTR + col] = h4;
        *(ushort4*)&sA_l[row * LSTR + col] = l4;
    }
    __syncthreads();

    f32x4 acc[2][4];
#pragma unroll
    for (int r = 0; r < 2; r++)
#pragma unroll
        for (int c = 0; c < 4; c++) acc[r][c] = (f32x4){0.f, 0.f, 0.f, 0.f};

#pragma unroll
    for (int ks = 0; ks < KSTEPS; ks++) {
        int ko = ks * 32 + q * 8;
        short8 ah[2], al[2], bh[4], bl[4];
#pragma unroll
        for (int c = 0; c < 4; c++) {
            int cb = 4 * w + c;
            size_t off = ((size_t)(ks * 16 + cb) * 64 + lane) * 8;
            bh[c] = __builtin_bit_cast(short8, *(const uint4*)(Bswh + off));
            bl[c] = __builtin_bit_cast(short8, *(const uint4*)(Bswl + off));
        }
#pragma unroll
        for (int r = 0; r < 2; r++) {
            int ao = (16 * r + m) * LSTR + ko;
            ah[r] = __builtin_bit_cast(short8, *(uint4*)&sA_h[ao]);
            al[r] = __builtin_bit_cast(short8, *(uint4*)&sA_l[ao]);
        }
#pragma unroll
        for (int r = 0; r < 2; r++)
#pragma unroll
            for (int c = 0; c < 4; c++) {
                acc[r][c] = __builtin_amdgcn_mfma_f32_16x16x32_bf16(ah[r], bh[c], acc[r][c], 0, 0, 0);
                acc[r][c] = __builtin_amdgcn_mfma_f32_16x16x32_bf16(ah[r], bl[c], acc[r][c], 0, 0, 0);
                acc[r][c] = __builtin_amdgcn_mfma_f32_16x16x32_bf16(al[r], bh[c], acc[r][c], 0, 0, 0);
            }
    }
    int colbase = (w & 1) * 64;
    if (w < 2) {
#pragma unroll
        for (int r = 0; r < 2; r++)
#pragma unroll
            for (int c = 0; c < 4; c++) {
                int col = colbase + 16 * c + m;
#pragma unroll
                for (int i = 0; i < 4; i++) {
                    int row = n0 + 16 * r + 4 * q + i;
                    if (row < N) {
                        __hip_bfloat16 h = __float2bfloat16(acc[r][c][i]);
                        U16[(size_t)row * HID + col] = *(unsigned short*)&h;
                    }
                }
            }
    } else {
#pragma unroll
        for (int r = 0; r < 2; r++)
#pragma unroll
            for (int c = 0; c < 4; c++) {
                int col = colbase + 16 * c + m;
#pragma unroll
                for (int i = 0; i < 4; i++) {
                    int row = n0 + 16 * r + 4 * q + i;
                    if (row < N) V[(size_t)row * HID + col] = acc[r][c][i];
                }
            }
    }
}

// ---------------- aggregation (R8-proven: 8 nodes/block, 32-lane uint2, 8-deep,
// full-wave coalesced Z stores) + fused BN stats -- byte-identical to R10. ----------------
__global__ __launch_bounds__(256) void agg_kernel(const unsigned short* __restrict__ U16,
                                                  const float* __restrict__ V,
                                                  const float* __restrict__ bias,
                                                  const int* __restrict__ counts,
                                                  const int* __restrict__ offsets,
                                                  const int* __restrict__ esrc,
                                                  float* __restrict__ Z,
                                                  float* __restrict__ psum,
                                                  float* __restrict__ psumsq, int N) {
    int grp = threadIdx.x >> 5;
    int l32 = threadIdx.x & 31;
    int n = blockIdx.x * 8 + grp;
    bool valid = (n < N);
    f32x4 z = (f32x4){0.f, 0.f, 0.f, 0.f};

    if (valid) {
        int deg = counts[n];
        int st = offsets[n];
        int co = 4 * l32;

        auto cvt = [](uint2 raw) -> f32x4 {
            f32x4 v;
            v[0] = __uint_as_float(raw.x << 16);
            v[1] = __uint_as_float(raw.x & 0xffff0000u);
            v[2] = __uint_as_float(raw.y << 16);
            v[3] = __uint_as_float(raw.y & 0xffff0000u);
            return v;
        };

        f32x4 a0 = {0,0,0,0}, a1 = {0,0,0,0}, a2 = {0,0,0,0}, a3 = {0,0,0,0};
        f32x4 a4 = {0,0,0,0}, a5 = {0,0,0,0}, a6 = {0,0,0,0}, a7 = {0,0,0,0};
        int i = 0;
        for (; i + 7 < deg; i += 8) {
            int s0 = esrc[st + i + 0], s1 = esrc[st + i + 1];
            int s2 = esrc[st + i + 2], s3 = esrc[st + i + 3];
            int s4 = esrc[st + i + 4], s5 = esrc[st + i + 5];
            int s6 = esrc[st + i + 6], s7 = esrc[st + i + 7];
            uint2 r0 = *(const uint2*)(U16 + (size_t)s0 * HID + co);
            uint2 r1 = *(const uint2*)(U16 + (size_t)s1 * HID + co);
            uint2 r2 = *(const uint2*)(U16 + (size_t)s2 * HID + co);
            uint2 r3 = *(const uint2*)(U16 + (size_t)s3 * HID + co);
            uint2 r4 = *(const uint2*)(U16 + (size_t)s4 * HID + co);
            uint2 r5 = *(const uint2*)(U16 + (size_t)s5 * HID + co);
            uint2 r6 = *(const uint2*)(U16 + (size_t)s6 * HID + co);
            uint2 r7 = *(const uint2*)(U16 + (size_t)s7 * HID + co);
            a0 += cvt(r0); a1 += cvt(r1); a2 += cvt(r2); a3 += cvt(r3);
            a4 += cvt(r4); a5 += cvt(r5); a6 += cvt(r6); a7 += cvt(r7);
        }
        for (; i + 3 < deg; i += 4) {
            int s0 = esrc[st + i + 0], s1 = esrc[st + i + 1];
            int s2 = esrc[st + i + 2], s3 = esrc[st + i + 3];
            uint2 r0 = *(const uint2*)(U16 + (size_t)s0 * HID + co);
            uint2 r1 = *(const uint2*)(U16 + (size_t)s1 * HID + co);
            uint2 r2 = *(const uint2*)(U16 + (size_t)s2 * HID + co);
            uint2 r3 = *(const uint2*)(U16 + (size_t)s3 * HID + co);
            a0 += cvt(r0); a1 += cvt(r1); a2 += cvt(r2); a3 += cvt(r3);
        }
        for (; i < deg; i++) {
            uint2 r0 = *(const uint2*)(U16 + (size_t)esrc[st + i] * HID + co);
            a0 += cvt(r0);
        }
        f32x4 acc = ((a0 + a1) + (a2 + a3)) + ((a4 + a5) + (a6 + a7));
        float d = (float)(deg > 1 ? deg : 1);
        f32x4 vv = ((const f32x4*)V)[(size_t)n * 32 + l32];
        f32x4 bb = ((const f32x4*)bias)[l32];
        z = acc / d + vv + bb;
        ((f32x4*)Z)[(size_t)n * 32 + l32] = z;
    }

    // fused stats: reduce the block's 8 nodes, one atomic pass per block
    __shared__ f32x4 bs[256], bq[256];
    int t = threadIdx.x;
    bs[t] = z;
    bq[t] = z * z;
    __syncthreads();
#pragma unroll
    for (int off = 4; off > 0; off >>= 1) {
        if (grp < off) {
            bs[t] += bs[t + off * 32];
            bq[t] += bq[t + off * 32];
        }
        __syncthreads();
    }
    if (grp == 0) {
        int slot = blockIdx.x & (NSB - 1);
        float* ps = psum + (size_t)slot * HID + 4 * l32;
        float* pq = psumsq + (size_t)slot * HID + 4 * l32;
        f32x4 s = bs[t];
        f32x4 qq = bq[t];
#pragma unroll
        for (int j = 0; j < 4; j++) {
            atomicAdd(&ps[j], s[j]);
            atomicAdd(&pq[j], qq[j]);
        }
    }
}

// ---------------- BN+ReLU + pool + MLP head (sc/sh precomputed; 256 threads,
// 2x-split pool loop from R10) ----------------
__global__ __launch_bounds__(256) void pool_head_kernel(const float* __restrict__ Z,
                                                        const float* __restrict__ scsh,
                                                        const int* __restrict__ batch,
                                                        const float* __restrict__ Wh1,
                                                        const float* __restrict__ bh1,
                                                        const float* __restrict__ Wh2,
                                                        const float* __restrict__ bh2,
                                                        float* __restrict__ out, int N) {
    int gph = blockIdx.x;
    __shared__ int bounds[2];
    __shared__ float pp[2][HID];
    int t = threadIdx.x;
    int ch = t & 127;
    int half = t >> 7;
    if (t < 2) {
        int target = gph + t;
        int lo = 0, hi = N;
        while (lo < hi) {
            int mid = (lo + hi) >> 1;
            if (batch[mid] < target) lo = mid + 1;
            else hi = mid;
        }
        bounds[t] = lo;
    }
    float sc = scsh[ch];
    float sh = scsh[HID + ch];
    __syncthreads();
    int start = bounds[0], end = bounds[1];
    // 2x-split pool loop: half h handles nodes start+h, start+h+2, ...
    {
        float s = 0.f;
        for (int n = start + half; n < end; n += 2)
            s += fmaxf(fmaf(Z[(size_t)n * HID + ch], sc, sh), 0.f);
        pp[half][ch] = s;
    }
    __syncthreads();
    if (t < HID)
        pp[0][t] = (pp[0][t] + pp[1][t]) / fmaxf((float)(end - start), 1.f);
    __syncthreads();
    if (t < 64) {
        float acc = bh1[t];
        for (int k = 0; k < 128; k++) acc = fmaf(pp[0][k], Wh1[k * 64 + t], acc);
        acc = fmaxf(acc, 0.f);
        float prod = acc * Wh2[t];
        for (int off = 32; off > 0; off >>= 1) prod += __shfl_down(prod, off);
        if (t == 0) out[gph] = prod + bh2[0];
    }
}

extern "C" void kernel_launch(void* const* d_in, const int* in_sizes, int n_in,
                              void* d_out, int out_size, void* d_ws, size_t ws_size,
                              hipStream_t stream) {
    const float* x = (const float*)d_in[0];
    const int* ei = (const int*)d_in[1];
    const int* batch = (const int*)d_in[2];
    const float* Wn[3] = {(const float*)d_in[3], (const float*)d_in[8], (const float*)d_in[13]};
    const float* bb[3] = {(const float*)d_in[4], (const float*)d_in[9], (const float*)d_in[14]};
    const float* Wr[3] = {(const float*)d_in[5], (const float*)d_in[10], (const float*)d_in[15]};
    const float* gg[3] = {(const float*)d_in[6], (const float*)d_in[11], (const float*)d_in[16]};
    const float* be[3] = {(const float*)d_in[7], (const float*)d_in[12], (const float*)d_in[17]};
    const float* Wh1 = (const float*)d_in[18];
    const float* bh1 = (const float*)d_in[19];
    const float* Wh2 = (const float*)d_in[20];
    const float* bh2 = (const float*)d_in[21];
    float* out = (float*)d_out;

    const int N = in_sizes[2];       // 50000
    const int NE = in_sizes[1] / 2;  // 800000
    const int NG = out_size;         // 1000
    const int K0 = in_sizes[0] / N;  // 78
    const int K0pad = (K0 <= 96) ? 96 : 128;  // template-dispatched KPAD (K0 <= 128)

    const int* src = ei;
    const int* dst = ei + NE;

    // bucket geometry: <=512 buckets, <=512 nodes/bucket (N<=262144)
    int shift = 7;
    int nbuck = (N + 127) >> 7;
    while (nbuck > 512) { shift++; nbuck = (N + (1 << shift) - 1) >> shift; }

    char* w = (char*)d_ws;
    auto alloc = [&](size_t bytes) -> void* {
        void* p = (void*)w;
        w += (bytes + 255) & ~(size_t)255;
        return p;
    };
    unsigned short* bufU16 = (unsigned short*)alloc((size_t)N * HID * 2);
    float* bufV = (float*)alloc((size_t)N * HID * 4);
    float* bufZ = (float*)alloc((size_t)N * HID * 4);
    float* xp = (float*)alloc((size_t)N * K0pad * 4);
    unsigned short* BTh[3];
    unsigned short* BTl[3];
    BTh[0] = (unsigned short*)alloc((size_t)256 * K0pad * 2);
    BTl[0] = (unsigned short*)alloc((size_t)256 * K0pad * 2);
    BTh[1] = (unsigned short*)alloc((size_t)256 * HID * 2);
    BTl[1] = (unsigned short*)alloc((size_t)256 * HID * 2);
    BTh[2] = (unsigned short*)alloc((size_t)256 * HID * 2);
    BTl[2] = (unsigned short*)alloc((size_t)256 * HID * 2);
    int* counts = (int*)alloc((size_t)N * 4);
    int* offsets = (int*)alloc((size_t)(N + 1) * 4);
    int* esrc = (int*)alloc((size_t)NE * 4);
    int* bcnt = (int*)alloc((size_t)512 * 16 * 4);   // padded: 1 counter / 64B line
    int* bcur = (int*)alloc((size_t)512 * 16 * 4);
    int* bbase = (int*)alloc((size_t)(512 + 1) * 4);
    float* pstats = (float*)alloc((size_t)3 * 2 * NSB * HID * 4);
    float* scsh = (float*)alloc((size_t)3 * 2 * HID * 4);
    // ebuf (NE*8 = 6.4MB) only live during CSR build, before bufZ's first write -> alias.
    uint2* ebuf = (uint2*)bufZ;
    (void)ws_size;
    (void)n_in;

    const int npstats = 3 * 2 * NSB * HID;

    // ---- prep (zero bucket counters + zero pstats + pad x + swizzled weights) ----
    size_t prep_total = (size_t)N * K0pad;
    prep_kernel<<<(prep_total + 255) / 256, 256, 0, stream>>>(
        x, xp, bcnt, nbuck * 16, pstats, npstats,
        Wn[0], Wr[0], Wn[1], Wr[1], Wn[2], Wr[2],
        BTh[0], BTl[0], BTh[1], BTl[1], BTh[2], BTl[2], N, K0, K0pad);

    // ---- CSR via bucketed counting sort ----
    binA_kernel<<<NBLK_BIN, 256, 0, stream>>>(dst, bcnt, NE, nbuck, shift);
    bucket_scan_kernel<<<1, 512, 0, stream>>>(bcnt, bbase, bcur, nbuck);
    binB_kernel<<<NBLK_BIN, 256, 0, stream>>>(src, dst, bcur, ebuf, NE, nbuck, shift);
    binC_kernel<<<nbuck, 512, 0, stream>>>(ebuf, bbase, counts, offsets, esrc, N, shift);

    // ---- 3 SAGE layers: gemm(prev sc/sh) -> agg(+fused stats) -> bnfin(sc/sh) ----
    int gblocks = (N + 31) / 32;
    int ablocks = (N + 7) / 8;
    for (int l = 0; l < 3; l++) {
        const float* Ain = (l == 0) ? xp : bufZ;
        int Kpad = (l == 0) ? K0pad : HID;
        const float* pscsh = (l == 0) ? (const float*)nullptr : scsh + (size_t)(l - 1) * 2 * HID;
        if (Kpad == 96)
            gemm_kernel<96><<<gblocks, 256, 0, stream>>>(Ain, pscsh,
                                                         BTh[l], BTl[l], bufU16, bufV, N);
        else
            gemm_kernel<128><<<gblocks, 256, 0, stream>>>(Ain, pscsh,
                                                          BTh[l], BTl[l], bufU16, bufV, N);
        agg_kernel<<<ablocks, 256, 0, stream>>>(bufU16, bufV, bb[l], counts, offsets, esrc, bufZ,
                                                pstats + (size_t)l * 2 * NSB * HID,
                                                pstats + (size_t)l * 2 * NSB * HID + NSB * HID, N);
        bnfin_kernel<<<1, 256, 0, stream>>>(pstats + (size_t)l * 2 * NSB * HID,
                                            pstats + (size_t)l * 2 * NSB * HID + NSB * HID,
                                            gg[l], be[l], scsh + (size_t)l * 2 * HID, N);
    }

    // ---- BN+ReLU + pool + head (sc/sh precomputed) ----
    pool_head_kernel<<<NG, 256, 0, stream>>>(bufZ, scsh + (size_t)2 * 2 * HID,
                                             batch, Wh1, bh1, Wh2, bh2, out, N);
}